// Round 18
// baseline (267.465 us; speedup 1.0000x reference)
//
#include <hip/hip_runtime.h>

#define EPS 1e-5f
#define L2E 1.442695041f

typedef __attribute__((ext_vector_type(8))) short short8;
typedef __attribute__((ext_vector_type(4))) float f32x4;
#define MFMA16(a,b,c) __builtin_amdgcn_mfma_f32_16x16x32_bf16(a,b,c,0,0,0)

typedef float __attribute__((may_alias)) fal;
typedef unsigned short __attribute__((may_alias)) sal;
typedef unsigned int __attribute__((may_alias)) u32al;
typedef uint4 __attribute__((may_alias)) u4al;
typedef f32x4 __attribute__((may_alias)) f4al;

union U8 { short8 s; uint4 u; };

__device__ __forceinline__ float wred(float v){
#pragma unroll
  for(int m=32;m>=1;m>>=1) v += __shfl_xor(v,m,64);
  return v;
}

__device__ __forceinline__ unsigned short f2bf(float f){
  union{unsigned int i; float x;}v; v.x=f;
  unsigned int u=v.i;
  unsigned int r=(u + 0x7fffu + ((u>>16)&1u))>>16;
  return (unsigned short)r;
}
// single-instruction packed f32->bf16 (RNE). Verified bit-identical to f2bf pair on HW (R2==R3).
__device__ __forceinline__ unsigned cvtpk(float lo, float hi){
  unsigned r; asm("v_cvt_pk_bf16_f32 %0, %1, %2" : "=v"(r) : "v"(lo), "v"(hi)); return r;
}
__device__ __forceinline__ float bflo(unsigned int u){
  union{unsigned int i; float x;}v; v.i=u<<16; return v.x;
}
__device__ __forceinline__ float bfhi(unsigned int u){
  union{unsigned int i; float x;}v; v.i=u&0xffff0000u; return v.x;
}

// k-row permutation #1 (second-layer frags): kappa = 8g+e -> feature (e<4)?4g+e:16+4g+e-4.
__device__ __host__ __forceinline__ int kperm(int k){
  int g=k>>3, e=k&7;
  return (e<4) ? 4*g+e : 16+4*g+(e-4);
}
// k-row permutation #2 (y1-GEMM): kglobal = kc*32+8*gamma+e -> feature 16*(2kc+(e>>2))+4*gamma+(e&3).
__device__ __host__ __forceinline__ int kpermD(int kg){
  int kc=kg>>5, kk=kg&31, gm=kk>>3, e=kk&7;
  return 16*(2*kc+(e>>2)) + 4*gm + (e&3);
}

// ---------------- kT: build bf16 transposed weights for MFMA b-fragments
__global__ __launch_bounds__(256) void kT(const float* __restrict__ kW2, const float* __restrict__ qW2,
                                          const float* __restrict__ vW2, const float* __restrict__ dW1,
                                          const float* __restrict__ dW2,
                                          unsigned short* __restrict__ wbf){
  for(int idx=threadIdx.x; idx<2048; idx+=256){
    int k=idx&31, c=idx>>5;            // c = output col (0-63), k = frag k-slot (0-31)
    int f=kperm(k);                    // original W2 row
    wbf[c*32+k]       = f2bf(kW2[f*64+c]);
    wbf[2048+c*32+k]  = f2bf(qW2[f*64+c]);
    wbf[4096+c*32+k]  = f2bf(vW2[f*64+c]);
  }
  for(int idx=threadIdx.x; idx<2048; idx+=256){
    int f=idx&31, kg=idx>>5;           // f = output col (0-31), kg = global k-slot (0-63)
    wbf[6144 + f*64 + kg] = f2bf(dW1[kpermD(kg)*32 + f]);
  }
  for(int idx=threadIdx.x; idx<512; idx+=256){
    int k=idx>>4, f=idx&15;            // dW2 is [32][16]
    wbf[8192 + f*32 + k] = f2bf(dW2[idx]);
  }
}

// ---------------- kA: input moments (63 accumulators), block partials [63][512]
__global__ __launch_bounds__(256) void kA(const float* __restrict__ rot, const float* __restrict__ tra,
                                          float* __restrict__ pA, int N){
  float a[63];
#pragma unroll
  for(int i=0;i<63;i++) a[i]=0.f;
  int stride = gridDim.x*blockDim.x;
  for(int row=blockIdx.x*blockDim.x+threadIdx.x; row<N; row+=stride){
    float t[3], r[9];
#pragma unroll
    for(int i=0;i<3;i++) t[i]=tra[row*3+i];
#pragma unroll
    for(int i=0;i<9;i++) r[i]=rot[row*9+i];
#pragma unroll
    for(int i=0;i<3;i++) a[i]+=t[i];
#pragma unroll
    for(int i=0;i<3;i++)
#pragma unroll
      for(int j=i;j<3;j++) a[3 + i*3 - (i*(i-1))/2 + (j-i)] += t[i]*t[j];
#pragma unroll
    for(int i=0;i<9;i++) a[9+i]+=r[i];
#pragma unroll
    for(int i=0;i<9;i++)
#pragma unroll
      for(int j=i;j<9;j++) a[18 + i*9 - (i*(i-1))/2 + (j-i)] += r[i]*r[j];
  }
#pragma unroll
  for(int i=0;i<63;i++) a[i]=wred(a[i]);
  __shared__ __align__(16) float lds[4][63];
  int wave=threadIdx.x>>6, lane=threadIdx.x&63;
  if(lane==0){
#pragma unroll
    for(int i=0;i<63;i++) lds[wave][i]=a[i];
  }
  __syncthreads();
  int t=threadIdx.x;
  if(t<63) pA[t*gridDim.x + blockIdx.x] = lds[0][t]+lds[1][t]+lds[2][t]+lds[3][t];
}

// ---------------- kA2: reduce moments -> folded BN1 scale/bias -> bf16 first-layer A-frags.
__global__ __launch_bounds__(256) void kA2(const float* __restrict__ pA, int nb,
    const float* __restrict__ kW1, const float* __restrict__ kg, const float* __restrict__ kb,
    const float* __restrict__ qW1, const float* __restrict__ qg, const float* __restrict__ qb,
    const float* __restrict__ vW1, const float* __restrict__ vg, const float* __restrict__ vb,
    float* __restrict__ cst, unsigned short* __restrict__ wA, float invN){
  __shared__ __align__(16) float tmp[63][4];
  __shared__ __align__(16) float mom[63];
  __shared__ __align__(16) float sSc[96];
  __shared__ __align__(16) float sBi[96];
  int t=threadIdx.x;
  if(t<252){
    int f=t>>2, q=t&3;
    int per=nb/4;
    float s=0.f;
    for(int i=0;i<per;i++) s+=pA[f*nb + q*per + i];
    tmp[f][q]=s;
  }
  __syncthreads();
  if(t<63) mom[t]=tmp[t][0]+tmp[t][1]+tmp[t][2]+tmp[t][3];
  __syncthreads();
  if(t<96){
    int net=t>>5, j=t&31;
    const float* W1; const float* g; const float* b; int din, sbase, mbase, obase;
    if(net==0){W1=kW1;g=kg;b=kb;din=3;sbase=0;mbase=3;obase=0;}
    else if(net==1){W1=qW1;g=qg;b=qb;din=9;sbase=9;mbase=18;obase=64;}
    else {W1=vW1;g=vg;b=vb;din=3;sbase=0;mbase=3;obase=128;}
    float mean=0.f, ex2=0.f;
    for(int i=0;i<din;i++){
      float wi=W1[i*32+j];
      mean += mom[sbase+i]*wi;
      int rowb = mbase + i*din - (i*(i-1))/2;
      for(int i2=i;i2<din;i2++){
        float w2=W1[i2*32+j];
        float m=mom[rowb + (i2-i)];
        ex2 += ((i2==i)?1.f:2.f)*wi*w2*m;
      }
    }
    mean*=invN; ex2*=invN;
    float var=ex2-mean*mean;
    float sc=g[j]*rsqrtf(var+EPS);
    float bi=b[j]-mean*sc;
    cst[obase+j]=sc; cst[obase+32+j]=bi;
    sSc[net*32+j]=sc; sBi[net*32+j]=bi;
  }
  __syncthreads();
  for(int i=threadIdx.x; i<3072; i+=256){
    int frag=i>>9, m=(i>>5)&15, k=i&31;
    int net=frag>>1, half=frag&1;
    int f = half*16+m;
    float v=0.f;
    if(net==0){
      if(k<3) v=kW1[k*32+f]*sSc[f];
      else if(k==3) v=sBi[f];
    } else if(net==1){
      if(k>=4 && k<13) v=qW1[(k-4)*32+f]*sSc[32+f];
      else if(k==3) v=sBi[32+f];
    } else {
      if(k<3) v=vW1[k*32+f]*sSc[64+f];
      else if(k==3) v=sBi[64+f];
    }
    wA[i]=f2bf(v);
  }
}

// ---------------- kRed: reduce per-block {sum,sumsq} partials -> BN scale/bias
__global__ __launch_bounds__(256) void kRed(const float* __restrict__ part, int nf, int nb,
    const float* __restrict__ g, const float* __restrict__ b, float* __restrict__ cstOut, float invN){
  int f=blockIdx.x;
  float s1=0.f,s2=0.f;
  for(int i=threadIdx.x;i<nb;i+=256){ s1+=part[f*nb+i]; s2+=part[(nf+f)*nb+i]; }
  s1=wred(s1); s2=wred(s2);
  __shared__ __align__(16) float l1[4],l2[4];
  int wave=threadIdx.x>>6;
  if((threadIdx.x&63)==0){l1[wave]=s1;l2[wave]=s2;}
  __syncthreads();
  if(threadIdx.x==0){
    float a=l1[0]+l1[1]+l1[2]+l1[3];
    float c=l2[0]+l2[1]+l2[2]+l2[3];
    float mean=a*invN;
    float var=c*invN-mean*mean;
    float sc=g[f]*rsqrtf(var+EPS);
    float bi=b[f]-mean*sc;
    cstOut[f]=sc; cstOut[nf+f]=bi;
  }
}

// ---------------- kHeavyM: full-MFMA per-row pipeline -> y1(bf16) + BN-d1 stats
// Software-pipelined: tile it+1's input loads + xB pack + first-layer MFMAs are issued
// between tile it's k/q/v MFMAs and softmax (independent -> MFMA/VALU pipes overlap).
// Tree reductions for softmax max/sum (depth 4 instead of serial 15/16).
__global__ __launch_bounds__(256) void kHeavyM(
    const float* __restrict__ rot, const float* __restrict__ tra,
    const unsigned short* __restrict__ wA, const unsigned short* __restrict__ wbf,
    const float* __restrict__ kb2, const float* __restrict__ qb2, const float* __restrict__ vb2,
    unsigned short* __restrict__ y1o, float* __restrict__ pB, int N, int nb4)
{
  __shared__ __align__(16) unsigned short sbK[2048];   // kW2T[64][32] chunk-swizzled
  __shared__ __align__(16) unsigned short sbQ[2048];
  __shared__ __align__(16) unsigned short sbV[2048];
  __shared__ __align__(16) unsigned short sbD[2048];   // dW1T[32][64] chunk-swizzled (kpermD rows)
  __shared__ __align__(16) unsigned short sA[3072];    // first-layer A-frags [6][16][32] chunk-swizzled
  __shared__ __align__(16) sal ybuf[4][640];           // per-wave y1 stage [16][40]
  for(int i=threadIdx.x;i<2048;i+=256){
    int e=i&7;
    int rK=i>>5, clK=(i>>3)&3;
    int dK = rK*32 + ((clK^(rK&3))<<3) + e;
    sbK[dK]=wbf[i]; sbQ[dK]=wbf[2048+i]; sbV[dK]=wbf[4096+i];
    int rD=i>>6, clD=(i>>3)&7;
    int dD = rD*64 + ((clD^(rD&7))<<3) + e;
    sbD[dD]=wbf[6144+i];
  }
  for(int i=threadIdx.x;i<3072;i+=256){
    int frag=i>>9, m=(i>>5)&15, k=i&31;
    int cl=k>>3, e=k&7;
    sA[frag*512 + m*32 + ((cl^(m&3))<<3) + e] = wA[i];
  }
  int wv=threadIdx.x>>6, lane=threadIdx.x&63;
  int c=lane&15, g=lane>>4;

  // hoisted bias C-operands (loop-invariant)
  f32x4 cK[4],cQ[4],cV[4];
#pragma unroll
  for(int t=0;t<4;t++){
    cK[t]=*(const f4al*)(kb2+16*t+4*g);
    cQ[t]=*(const f4al*)(qb2+16*t+4*g);
    cV[t]=*(const f4al*)(vb2+16*t+4*g);
  }

  float stS0=0.f, stS1=0.f, stQ0=0.f, stQ1=0.f;
  __syncthreads();

  sal* yw = ybuf[wv];
  int wsw = (g^(c&3))<<3;           // chunk swizzle offset for frag reads
  f32x4 z4 = {0.f,0.f,0.f,0.f};
  int tileBase = blockIdx.x*1024 + wv*16;

  // ---- preamble: tile 0 inputs -> xB -> first-layer frags ----
  U8 aK,aQ,aV;
  {
    int r0 = tileBase + c;
    int lr = (r0 < N) ? r0 : (N-1);
    float t0=tra[lr*3+0], t1=tra[lr*3+1], t2=tra[lr*3+2];
    float r9[9];
#pragma unroll
    for(int i=0;i<9;i++) r9[i]=rot[lr*9+i];
    U8 xB;
    unsigned a0=cvtpk(t0,t1), a1=cvtpk(t2,1.f), a2=cvtpk(r9[0],r9[1]), a3=cvtpk(r9[2],r9[3]);
    unsigned b0=cvtpk(r9[4],r9[5]), b1=cvtpk(r9[6],r9[7]), b2=cvtpk(r9[8],0.f);
    xB.u = make_uint4((g==0)?a0:((g==1)?b0:0u),
                      (g==0)?a1:((g==1)?b1:0u),
                      (g==0)?a2:((g==1)?b2:0u),
                      (g==0)?a3:0u);
#pragma unroll
    for(int nt=0;nt<3;nt++){
      U8 A1,A2;
      A1.u = *(const u4al*)&sA[(nt*2+0)*512 + c*32 + wsw];
      A2.u = *(const u4al*)&sA[(nt*2+1)*512 + c*32 + wsw];
      f32x4 d1 = MFMA16(A1.s, xB.s, z4);
      f32x4 d2 = MFMA16(A2.s, xB.s, z4);
#pragma unroll
      for(int rg=0;rg<4;rg++){ d1[rg]=fmaxf(d1[rg],0.f); d2[rg]=fmaxf(d2[rg],0.f); }
      uint4 u = make_uint4(cvtpk(d1[0],d1[1]),cvtpk(d1[2],d1[3]),
                           cvtpk(d2[0],d2[1]),cvtpk(d2[2],d2[3]));
      if(nt==0) aK.u=u; else if(nt==1) aQ.u=u; else aV.u=u;
    }
  }

  for(int it=0; it<16; ++it, tileBase += 64){
    if(tileBase >= N) break;             // no barriers inside loop (wave-private LDS)
    int row = tileBase + c;
    bool vrow = row < N;

    // ---- issue next tile's input loads FIRST (latency hidden under current MFMAs) ----
    float nt0,nt1,nt2, nr[9];
    {
      int r2 = tileBase + 64 + c;
      int lr2 = (r2 < N) ? r2 : (N-1);
      nt0=tra[lr2*3+0]; nt1=tra[lr2*3+1]; nt2=tra[lr2*3+2];
#pragma unroll
      for(int i=0;i<9;i++) nr[i]=rot[lr2*9+i];
    }

    // ---- current tile: swapped k,q,v GEMMs -> s-values IN-LANE per row ----
    f32x4 s4[4], av[4];
#pragma unroll
    for(int t=0;t<4;t++){
      U8 bk, bq, bv;
      bk.u = *(const u4al*)&sbK[(t*16+c)*32 + wsw];
      bq.u = *(const u4al*)&sbQ[(t*16+c)*32 + wsw];
      bv.u = *(const u4al*)&sbV[(t*16+c)*32 + wsw];
      f32x4 ak = MFMA16(bk.s, aK.s, cK[t]);
      f32x4 aq = MFMA16(bq.s, aQ.s, cQ[t]);
      av[t]    = MFMA16(bv.s, aV.s, cV[t]);
#pragma unroll
      for(int rg=0;rg<4;rg++) s4[t][rg]=ak[rg]*aq[rg];
    }

    // ---- next tile: xB pack + first-layer MFMAs (independent of softmax below;
    //      scheduler overlaps this MFMA-pipe work with the VALU softmax) ----
    U8 aKn,aQn,aVn;
    {
      U8 xB;
      unsigned a0=cvtpk(nt0,nt1), a1=cvtpk(nt2,1.f), a2=cvtpk(nr[0],nr[1]), a3=cvtpk(nr[2],nr[3]);
      unsigned b0=cvtpk(nr[4],nr[5]), b1=cvtpk(nr[6],nr[7]), b2=cvtpk(nr[8],0.f);
      xB.u = make_uint4((g==0)?a0:((g==1)?b0:0u),
                        (g==0)?a1:((g==1)?b1:0u),
                        (g==0)?a2:((g==1)?b2:0u),
                        (g==0)?a3:0u);
#pragma unroll
      for(int nt=0;nt<3;nt++){
        U8 A1,A2;
        A1.u = *(const u4al*)&sA[(nt*2+0)*512 + c*32 + wsw];
        A2.u = *(const u4al*)&sA[(nt*2+1)*512 + c*32 + wsw];
        f32x4 d1 = MFMA16(A1.s, xB.s, z4);
        f32x4 d2 = MFMA16(A2.s, xB.s, z4);
#pragma unroll
        for(int rg=0;rg<4;rg++){ d1[rg]=fmaxf(d1[rg],0.f); d2[rg]=fmaxf(d2[rg],0.f); }
        uint4 u = make_uint4(cvtpk(d1[0],d1[1]),cvtpk(d1[2],d1[3]),
                             cvtpk(d2[0],d2[1]),cvtpk(d2[2],d2[3]));
        if(nt==0) aKn.u=u; else if(nt==1) aQn.u=u; else aVn.u=u;
      }
    }

    // ---- softmax: pairwise-tree max/sum (depth 4) + 2 cross-group shfl rounds ----
    float m0,m1,m2_,m3,m4,m5,m6,m7;
    m0=fmaxf(s4[0][0],s4[0][1]); m1=fmaxf(s4[0][2],s4[0][3]);
    m2_=fmaxf(s4[1][0],s4[1][1]); m3=fmaxf(s4[1][2],s4[1][3]);
    m4=fmaxf(s4[2][0],s4[2][1]); m5=fmaxf(s4[2][2],s4[2][3]);
    m6=fmaxf(s4[3][0],s4[3][1]); m7=fmaxf(s4[3][2],s4[3][3]);
    m0=fmaxf(m0,m1); m2_=fmaxf(m2_,m3); m4=fmaxf(m4,m5); m6=fmaxf(m6,m7);
    m0=fmaxf(m0,m2_); m4=fmaxf(m4,m6);
    float mx=fmaxf(m0,m4);
    mx=fmaxf(mx,__shfl_xor(mx,16,64));
    mx=fmaxf(mx,__shfl_xor(mx,32,64));
    float m2 = mx*L2E;
    float ee[16];
#pragma unroll
    for(int t=0;t<4;t++)
#pragma unroll
      for(int rg=0;rg<4;rg++){
        float e = exp2f(fmaf(s4[t][rg], L2E, -m2));
        s4[t][rg]=e; ee[t*4+rg]=e;
      }
#pragma unroll
    for(int i=0;i<8;i++) ee[i]+=ee[i+8];
#pragma unroll
    for(int i=0;i<4;i++) ee[i]+=ee[i+4];
    float zz=(ee[0]+ee[1])+(ee[2]+ee[3]);
    zz+=__shfl_xor(zz,16,64);
    zz+=__shfl_xor(zz,32,64);
    float inv = 1.f/zz;

    // P = e*inv*v packed IN-LANE into the two y1 A-frags (kpermD labeling)
    U8 ap0, ap1;
    {
      float p[4][4];
#pragma unroll
      for(int t=0;t<4;t++)
#pragma unroll
        for(int rg=0;rg<4;rg++) p[t][rg]=s4[t][rg]*inv*av[t][rg];
      ap0.u = make_uint4(cvtpk(p[0][0],p[0][1]),cvtpk(p[0][2],p[0][3]),
                         cvtpk(p[1][0],p[1][1]),cvtpk(p[1][2],p[1][3]));
      ap1.u = make_uint4(cvtpk(p[2][0],p[2][1]),cvtpk(p[2][2],p[2][3]),
                         cvtpk(p[3][0],p[3][1]),cvtpk(p[3][2],p[3][3]));
    }

    // y1 = P @ dW1 (b-frags from chunk-swizzled sbD)
    f32x4 acy0=z4, acy1=z4;
    {
      int dsw0 = ((0*4+g)^(c&7))<<3;
      int dsw1 = ((1*4+g)^(c&7))<<3;
      U8 b00,b01,b10,b11;
      b00.u = *(const u4al*)&sbD[c*64 + dsw0];
      b01.u = *(const u4al*)&sbD[(16+c)*64 + dsw0];
      b10.u = *(const u4al*)&sbD[c*64 + dsw1];
      b11.u = *(const u4al*)&sbD[(16+c)*64 + dsw1];
      acy0 = MFMA16(ap0.s, b00.s, acy0);
      acy1 = MFMA16(ap0.s, b01.s, acy1);
      acy0 = MFMA16(ap1.s, b10.s, acy0);
      acy1 = MFMA16(ap1.s, b11.s, acy1);
    }
    // mask invalid rows
#pragma unroll
    for(int rg=0;rg<4;rg++){
      if(tileBase + 4*g + rg >= N){ acy0[rg]=0.f; acy1[rg]=0.f; }
    }
    // stats
#pragma unroll
    for(int rg=0;rg<4;rg++){
      stS0+=acy0[rg]; stQ0+=acy0[rg]*acy0[rg];
      stS1+=acy1[rg]; stQ1+=acy1[rg]*acy1[rg];
    }
    // y1 store via LDS (stride 40 shorts) -> coalesced 16B
#pragma unroll
    for(int rg=0;rg<4;rg++){
      int m=4*g+rg;
      unsigned pr2 = cvtpk(acy0[rg], acy1[rg]);
      yw[m*40 + c]      = (unsigned short)pr2;
      yw[m*40 + 16 + c] = (unsigned short)(pr2>>16);
    }
    {
      u4al vv = *(const u4al*)&yw[c*40 + 8*g];
      if(vrow) *(uint4*)(y1o + (size_t)row*32 + 8*g) = vv;
    }

    // rotate pipelined first-layer frags
    aK=aKn; aQ=aQn; aV=aVn;
  }
  // per-wave stat partials -> pB[f][blockIdx*4+wv]
  stS0+=__shfl_xor(stS0,16,64); stS0+=__shfl_xor(stS0,32,64);
  stS1+=__shfl_xor(stS1,16,64); stS1+=__shfl_xor(stS1,32,64);
  stQ0+=__shfl_xor(stQ0,16,64); stQ0+=__shfl_xor(stQ0,32,64);
  stQ1+=__shfl_xor(stQ1,16,64); stQ1+=__shfl_xor(stQ1,32,64);
  if(g==0){
    int b4 = blockIdx.x*4 + wv;
    pB[c*nb4 + b4]      = stS0;
    pB[(16+c)*nb4 + b4] = stS1;
    pB[(32+c)*nb4 + b4] = stQ0;
    pB[(48+c)*nb4 + b4] = stQ1;
  }
}

// ---------------- kCM: y1(bf16) -> BN-d1 -> ReLU -> dW2 (MFMA) -> y2(bf16) + stats
__global__ __launch_bounds__(256) void kCM(const unsigned short* __restrict__ y1,
    const float* __restrict__ cst, const unsigned short* __restrict__ wbf,
    unsigned short* __restrict__ y2o, float* __restrict__ pC, int N, int nb){
  __shared__ __align__(16) unsigned short ybuf[4][256];  // per-wave 16x16 bf16
  __shared__ __align__(16) float sStat[4][32];
  int wv=threadIdx.x>>6, lane=threadIdx.x&63;
  int c=lane&15, g=lane>>4;
  U8 bD2; bD2.u = *(const uint4*)(wbf + 8192 + c*32 + 8*g);
  float sc[8], bi[8];
#pragma unroll
  for(int i=0;i<8;i++){ sc[i]=cst[192+8*g+i]; bi[i]=cst[224+8*g+i]; }
  float stS=0.f, stQ=0.f;
  unsigned short* yb = ybuf[wv];
  int tileBase = blockIdx.x*1024 + wv*16;
  f32x4 z4 = {0.f,0.f,0.f,0.f};
  // prefetch iteration 0
  uint4 w;
  {
    int r0 = tileBase + c;
    int lr = (r0 < N) ? r0 : (N-1);
    w = *(const uint4*)(y1 + (size_t)lr*32 + 8*g);
  }
  for(int it=0; it<16; ++it, tileBase += 64){
    if(tileBase >= N) break;
    int row = tileBase + c;
    bool vrow = row < N;
    uint4 cur = w;
    // prefetch next iteration
    {
      int r2 = tileBase + 64 + c;
      int lr2 = (r2 < N) ? r2 : (N-1);
      w = *(const uint4*)(y1 + (size_t)lr2*32 + 8*g);
    }
    unsigned wu[4]={cur.x,cur.y,cur.z,cur.w};
    float h[8];
#pragma unroll
    for(int j=0;j<4;j++){ h[2*j]=bflo(wu[j]); h[2*j+1]=bfhi(wu[j]); }
#pragma unroll
    for(int i=0;i<8;i++){ float x=h[i]*sc[i]+bi[i]; h[i]=fmaxf(x,0.f); }
    U8 a;
    a.u = make_uint4(cvtpk(h[0],h[1]),cvtpk(h[2],h[3]),cvtpk(h[4],h[5]),cvtpk(h[6],h[7]));
    f32x4 acc = MFMA16(a.s, bD2.s, z4);
#pragma unroll
    for(int rg=0;rg<4;rg++){
      if(tileBase + 4*g + rg >= N) acc[rg]=0.f;
      stS+=acc[rg]; stQ+=acc[rg]*acc[rg];
    }
#pragma unroll
    for(int rg=0;rg<4;rg++){
      int m=4*g+rg;
      yb[(m*16 + c) ^ ((m&3)<<2)] = f2bf(acc[rg]);
    }
    {
      int idx = (c*16 + 4*g) ^ ((c&3)<<2);
      uint2 vv = *(uint2*)&yb[idx];
      if(vrow) *(uint2*)(y2o + (size_t)row*16 + 4*g) = vv;
    }
  }
  stS+=__shfl_xor(stS,16,64); stS+=__shfl_xor(stS,32,64);
  stQ+=__shfl_xor(stQ,16,64); stQ+=__shfl_xor(stQ,32,64);
  if(g==0){ sStat[wv][c]=stS; sStat[wv][16+c]=stQ; }
  __syncthreads();
  int t=threadIdx.x;
  if(t<32) pC[t*nb + blockIdx.x] = sStat[0][t]+sStat[1][t]+sStat[2][t]+sStat[3][t];
}

// ---------------- kD: y2(bf16) -> BN-d2 -> ReLU -> dW3+db3 -> sigmoid -> out
__global__ __launch_bounds__(256) void kD(const unsigned short* __restrict__ y2,
    const float* __restrict__ cst, const float* __restrict__ dW3, const float* __restrict__ db3,
    float* __restrict__ outp, int N){
  int row=blockIdx.x*256+threadIdx.x;
  if(row>=N) return;
  const uint4* src=(const uint4*)(y2+(size_t)row*16);
  uint4 q0=src[0],q1=src[1];
  unsigned int w[8]={q0.x,q0.y,q0.z,q0.w,q1.x,q1.y,q1.z,q1.w};
  float o=db3[0];
#pragma unroll
  for(int kk=0;kk<8;kk++){
    float lo=bflo(w[kk])*cst[256+2*kk]+cst[272+2*kk];
    float hi=bfhi(w[kk])*cst[256+2*kk+1]+cst[272+2*kk+1];
    lo=lo>0.f?lo:0.f; hi=hi>0.f?hi:0.f;
    o+=lo*dW3[2*kk]+hi*dW3[2*kk+1];
  }
  outp[row]=1.f/(1.f+__expf(-o));
}

extern "C" void kernel_launch(void* const* d_in, const int* in_sizes, int n_in,
                              void* d_out, int out_size, void* d_ws, size_t ws_size,
                              hipStream_t stream){
  const float* rot=(const float*)d_in[0];
  const float* tra=(const float*)d_in[1];
  const float* kW1=(const float*)d_in[2];
  const float* kg =(const float*)d_in[3];
  const float* kb =(const float*)d_in[4];
  const float* kW2=(const float*)d_in[5];
  const float* kb2=(const float*)d_in[6];
  const float* qW1=(const float*)d_in[7];
  const float* qg =(const float*)d_in[8];
  const float* qb =(const float*)d_in[9];
  const float* qW2=(const float*)d_in[10];
  const float* qb2=(const float*)d_in[11];
  const float* vW1=(const float*)d_in[12];
  const float* vg =(const float*)d_in[13];
  const float* vb =(const float*)d_in[14];
  const float* vW2=(const float*)d_in[15];
  const float* vb2=(const float*)d_in[16];
  const float* dW1=(const float*)d_in[17];
  const float* dg1=(const float*)d_in[18];
  const float* db1=(const float*)d_in[19];
  const float* dW2=(const float*)d_in[20];
  const float* dg2=(const float*)d_in[21];
  const float* db2=(const float*)d_in[22];
  const float* dW3=(const float*)d_in[23];
  const float* db3=(const float*)d_in[24];

  int N=in_sizes[0]/9;
  int nbH=(N+1023)/1024;
  int nb4=4*nbH;

  float* ws=(float*)d_ws;
  float* cst=ws;                         // [0,1024)
  float* pA =ws+1024;                    // 63*512 -> ends 33280
  float* pB =ws+33280;                   // [64][nb4]
  float* pC =pB+(size_t)64*nb4;          // [32][nbH]
  unsigned short* wbf=(unsigned short*)(pC+(size_t)32*nbH);  // 8704 shorts
  unsigned short* wA = wbf+8704;                              // 3072 shorts

  size_t y1off=(size_t)8<<20;            // bytes
  unsigned short* y1=(unsigned short*)((char*)d_ws + y1off);
  unsigned short* y2=(unsigned short*)((char*)d_ws + y1off + (size_t)N*64);
  float invN=1.f/(float)N;
  dim3 B(256);

  kT <<<dim3(1),   B,0,stream>>>(kW2,qW2,vW2,dW1,dW2,wbf);
  kA <<<dim3(512), B,0,stream>>>(rot,tra,pA,N);
  kA2<<<dim3(1),   B,0,stream>>>(pA,512,kW1,kg,kb,qW1,qg,qb,vW1,vg,vb,cst,wA,invN);

  kHeavyM<<<dim3(nbH),B,0,stream>>>(rot,tra,wA,wbf,kb2,qb2,vb2,y1,pB,N,nb4);
  kRed<<<dim3(32),B,0,stream>>>(pB,32,nb4,dg1,db1,cst+192,invN);
  kCM<<<dim3(nbH),B,0,stream>>>(y1,cst,wbf,y2,pC,N,nbH);
  kRed<<<dim3(16),B,0,stream>>>(pC,16,nbH,dg2,db2,cst+256,invN);
  kD <<<dim3((N+255)/256),B,0,stream>>>(y2,cst,dW3,db3,(float*)d_out,N);
}

// Round 19
// 237.274 us; speedup vs baseline: 1.1272x; 1.1272x over previous
//
#include <hip/hip_runtime.h>

#define EPS 1e-5f
#define L2E 1.442695041f

typedef __attribute__((ext_vector_type(8))) short short8;
typedef __attribute__((ext_vector_type(4))) float f32x4;
#define MFMA16(a,b,c) __builtin_amdgcn_mfma_f32_16x16x32_bf16(a,b,c,0,0,0)

typedef float __attribute__((may_alias)) fal;
typedef unsigned short __attribute__((may_alias)) sal;
typedef unsigned int __attribute__((may_alias)) u32al;
typedef uint4 __attribute__((may_alias)) u4al;
typedef f32x4 __attribute__((may_alias)) f4al;

union U8 { short8 s; uint4 u; };

__device__ __forceinline__ float wred(float v){
#pragma unroll
  for(int m=32;m>=1;m>>=1) v += __shfl_xor(v,m,64);
  return v;
}

__device__ __forceinline__ unsigned short f2bf(float f){
  union{unsigned int i; float x;}v; v.x=f;
  unsigned int u=v.i;
  unsigned int r=(u + 0x7fffu + ((u>>16)&1u))>>16;
  return (unsigned short)r;
}
// single-instruction packed f32->bf16 (RNE). Verified bit-identical to f2bf pair on HW (R2==R3).
__device__ __forceinline__ unsigned cvtpk(float lo, float hi){
  unsigned r; asm("v_cvt_pk_bf16_f32 %0, %1, %2" : "=v"(r) : "v"(lo), "v"(hi)); return r;
}
__device__ __forceinline__ float bflo(unsigned int u){
  union{unsigned int i; float x;}v; v.i=u<<16; return v.x;
}
__device__ __forceinline__ float bfhi(unsigned int u){
  union{unsigned int i; float x;}v; v.i=u&0xffff0000u; return v.x;
}

// k-row permutation #1 (second-layer frags): kappa = 8g+e -> feature (e<4)?4g+e:16+4g+e-4.
__device__ __host__ __forceinline__ int kperm(int k){
  int g=k>>3, e=k&7;
  return (e<4) ? 4*g+e : 16+4*g+(e-4);
}
// k-row permutation #2 (y1-GEMM): kglobal = kc*32+8*gamma+e -> feature 16*(2kc+(e>>2))+4*gamma+(e&3).
__device__ __host__ __forceinline__ int kpermD(int kg){
  int kc=kg>>5, kk=kg&31, gm=kk>>3, e=kk&7;
  return 16*(2*kc+(e>>2)) + 4*gm + (e&3);
}

// ---------------- kT: build bf16 transposed weights for MFMA b-fragments
__global__ __launch_bounds__(256) void kT(const float* __restrict__ kW2, const float* __restrict__ qW2,
                                          const float* __restrict__ vW2, const float* __restrict__ dW1,
                                          const float* __restrict__ dW2,
                                          unsigned short* __restrict__ wbf){
  for(int idx=threadIdx.x; idx<2048; idx+=256){
    int k=idx&31, c=idx>>5;            // c = output col (0-63), k = frag k-slot (0-31)
    int f=kperm(k);                    // original W2 row
    wbf[c*32+k]       = f2bf(kW2[f*64+c]);
    wbf[2048+c*32+k]  = f2bf(qW2[f*64+c]);
    wbf[4096+c*32+k]  = f2bf(vW2[f*64+c]);
  }
  for(int idx=threadIdx.x; idx<2048; idx+=256){
    int f=idx&31, kg=idx>>5;           // f = output col (0-31), kg = global k-slot (0-63)
    wbf[6144 + f*64 + kg] = f2bf(dW1[kpermD(kg)*32 + f]);
  }
  for(int idx=threadIdx.x; idx<512; idx+=256){
    int k=idx>>4, f=idx&15;            // dW2 is [32][16]
    wbf[8192 + f*32 + k] = f2bf(dW2[idx]);
  }
}

// ---------------- kA: input moments, 4 rows/thread with float4 loads (fully coalesced)
__global__ __launch_bounds__(256) void kA(const float* __restrict__ rot, const float* __restrict__ tra,
                                          float* __restrict__ pA, int N){
  float a[63];
#pragma unroll
  for(int i=0;i<63;i++) a[i]=0.f;
  int stride = gridDim.x*blockDim.x;
  int nch = N>>2;                       // N divisible by 4 (grid covers; guard below for tail)
  for(int ch=blockIdx.x*blockDim.x+threadIdx.x; ch<nch; ch+=stride){
    float tt[12], rr[36];
    {
      const float4* tp = (const float4*)(tra + (size_t)ch*12);
      const float4* rp = (const float4*)(rot + (size_t)ch*36);
#pragma unroll
      for(int i=0;i<3;i++) *(float4*)&tt[4*i]=tp[i];
#pragma unroll
      for(int i=0;i<9;i++) *(float4*)&rr[4*i]=rp[i];
    }
#pragma unroll
    for(int w=0;w<4;w++){
      const float* t=&tt[3*w];
      const float* r=&rr[9*w];
#pragma unroll
      for(int i=0;i<3;i++) a[i]+=t[i];
#pragma unroll
      for(int i=0;i<3;i++)
#pragma unroll
        for(int j=i;j<3;j++) a[3 + i*3 - (i*(i-1))/2 + (j-i)] += t[i]*t[j];
#pragma unroll
      for(int i=0;i<9;i++) a[9+i]+=r[i];
#pragma unroll
      for(int i=0;i<9;i++)
#pragma unroll
        for(int j=i;j<9;j++) a[18 + i*9 - (i*(i-1))/2 + (j-i)] += r[i]*r[j];
    }
  }
  // tail rows (N not divisible by 4): handled by first thread of grid
  if(blockIdx.x==0 && threadIdx.x==0){
    for(int row=(nch<<2); row<N; ++row){
      const float* t=tra+ (size_t)row*3;
      const float* r=rot+ (size_t)row*9;
#pragma unroll
      for(int i=0;i<3;i++) a[i]+=t[i];
#pragma unroll
      for(int i=0;i<3;i++)
#pragma unroll
        for(int j=i;j<3;j++) a[3 + i*3 - (i*(i-1))/2 + (j-i)] += t[i]*t[j];
#pragma unroll
      for(int i=0;i<9;i++) a[9+i]+=r[i];
#pragma unroll
      for(int i=0;i<9;i++)
#pragma unroll
        for(int j=i;j<9;j++) a[18 + i*9 - (i*(i-1))/2 + (j-i)] += r[i]*r[j];
    }
  }
#pragma unroll
  for(int i=0;i<63;i++) a[i]=wred(a[i]);
  __shared__ __align__(16) float lds[4][63];
  int wave=threadIdx.x>>6, lane=threadIdx.x&63;
  if(lane==0){
#pragma unroll
    for(int i=0;i<63;i++) lds[wave][i]=a[i];
  }
  __syncthreads();
  int t=threadIdx.x;
  if(t<63) pA[t*gridDim.x + blockIdx.x] = lds[0][t]+lds[1][t]+lds[2][t]+lds[3][t];
}

// ---------------- kA2: reduce moments -> folded BN1 scale/bias -> bf16 first-layer A-frags.
__global__ __launch_bounds__(256) void kA2(const float* __restrict__ pA, int nb,
    const float* __restrict__ kW1, const float* __restrict__ kg, const float* __restrict__ kb,
    const float* __restrict__ qW1, const float* __restrict__ qg, const float* __restrict__ qb,
    const float* __restrict__ vW1, const float* __restrict__ vg, const float* __restrict__ vb,
    float* __restrict__ cst, unsigned short* __restrict__ wA, float invN){
  __shared__ __align__(16) float tmp[63][4];
  __shared__ __align__(16) float mom[63];
  __shared__ __align__(16) float sSc[96];
  __shared__ __align__(16) float sBi[96];
  int t=threadIdx.x;
  if(t<252){
    int f=t>>2, q=t&3;
    int per=nb/4;
    float s=0.f;
    for(int i=0;i<per;i++) s+=pA[f*nb + q*per + i];
    tmp[f][q]=s;
  }
  __syncthreads();
  if(t<63) mom[t]=tmp[t][0]+tmp[t][1]+tmp[t][2]+tmp[t][3];
  __syncthreads();
  if(t<96){
    int net=t>>5, j=t&31;
    const float* W1; const float* g; const float* b; int din, sbase, mbase, obase;
    if(net==0){W1=kW1;g=kg;b=kb;din=3;sbase=0;mbase=3;obase=0;}
    else if(net==1){W1=qW1;g=qg;b=qb;din=9;sbase=9;mbase=18;obase=64;}
    else {W1=vW1;g=vg;b=vb;din=3;sbase=0;mbase=3;obase=128;}
    float mean=0.f, ex2=0.f;
    for(int i=0;i<din;i++){
      float wi=W1[i*32+j];
      mean += mom[sbase+i]*wi;
      int rowb = mbase + i*din - (i*(i-1))/2;
      for(int i2=i;i2<din;i2++){
        float w2=W1[i2*32+j];
        float m=mom[rowb + (i2-i)];
        ex2 += ((i2==i)?1.f:2.f)*wi*w2*m;
      }
    }
    mean*=invN; ex2*=invN;
    float var=ex2-mean*mean;
    float sc=g[j]*rsqrtf(var+EPS);
    float bi=b[j]-mean*sc;
    cst[obase+j]=sc; cst[obase+32+j]=bi;
    sSc[net*32+j]=sc; sBi[net*32+j]=bi;
  }
  __syncthreads();
  for(int i=threadIdx.x; i<3072; i+=256){
    int frag=i>>9, m=(i>>5)&15, k=i&31;
    int net=frag>>1, half=frag&1;
    int f = half*16+m;
    float v=0.f;
    if(net==0){
      if(k<3) v=kW1[k*32+f]*sSc[f];
      else if(k==3) v=sBi[f];
    } else if(net==1){
      if(k>=4 && k<13) v=qW1[(k-4)*32+f]*sSc[32+f];
      else if(k==3) v=sBi[32+f];
    } else {
      if(k<3) v=vW1[k*32+f]*sSc[64+f];
      else if(k==3) v=sBi[64+f];
    }
    wA[i]=f2bf(v);
  }
}

// ---------------- kRed: reduce per-block {sum,sumsq} partials -> BN scale/bias
__global__ __launch_bounds__(256) void kRed(const float* __restrict__ part, int nf, int nb,
    const float* __restrict__ g, const float* __restrict__ b, float* __restrict__ cstOut, float invN){
  int f=blockIdx.x;
  float s1=0.f,s2=0.f;
  for(int i=threadIdx.x;i<nb;i+=256){ s1+=part[f*nb+i]; s2+=part[(nf+f)*nb+i]; }
  s1=wred(s1); s2=wred(s2);
  __shared__ __align__(16) float l1[4],l2[4];
  int wave=threadIdx.x>>6;
  if((threadIdx.x&63)==0){l1[wave]=s1;l2[wave]=s2;}
  __syncthreads();
  if(threadIdx.x==0){
    float a=l1[0]+l1[1]+l1[2]+l1[3];
    float c=l2[0]+l2[1]+l2[2]+l2[3];
    float mean=a*invN;
    float var=c*invN-mean*mean;
    float sc=g[f]*rsqrtf(var+EPS);
    float bi=b[f]-mean*sc;
    cstOut[f]=sc; cstOut[nf+f]=bi;
  }
}

// ---------------- kHeavyM: full-MFMA per-row pipeline -> y1(bf16) + BN-d1 stats
// R16 structure (input prefetch, no deep pipeline) + biases as LDS C-operands
// (register diet: target VGPR <= 64) + tree softmax reductions.
__global__ __launch_bounds__(256) void kHeavyM(
    const float* __restrict__ rot, const float* __restrict__ tra,
    const unsigned short* __restrict__ wA, const unsigned short* __restrict__ wbf,
    const float* __restrict__ kb2, const float* __restrict__ qb2, const float* __restrict__ vb2,
    unsigned short* __restrict__ y1o, float* __restrict__ pB, int N, int nb4)
{
  __shared__ __align__(16) float sBias[192];
  __shared__ __align__(16) unsigned short sbK[2048];   // kW2T[64][32] chunk-swizzled
  __shared__ __align__(16) unsigned short sbQ[2048];
  __shared__ __align__(16) unsigned short sbV[2048];
  __shared__ __align__(16) unsigned short sbD[2048];   // dW1T[32][64] chunk-swizzled (kpermD rows)
  __shared__ __align__(16) unsigned short sA[3072];    // first-layer A-frags [6][16][32] chunk-swizzled
  __shared__ __align__(16) sal ybuf[4][640];           // per-wave y1 stage [16][40]
  if(threadIdx.x<192){
    int i=threadIdx.x;
    sBias[i] = (i<64)?kb2[i]:((i<128)?qb2[i-64]:vb2[i-128]);
  }
  for(int i=threadIdx.x;i<2048;i+=256){
    int e=i&7;
    int rK=i>>5, clK=(i>>3)&3;
    int dK = rK*32 + ((clK^(rK&3))<<3) + e;
    sbK[dK]=wbf[i]; sbQ[dK]=wbf[2048+i]; sbV[dK]=wbf[4096+i];
    int rD=i>>6, clD=(i>>3)&7;
    int dD = rD*64 + ((clD^(rD&7))<<3) + e;
    sbD[dD]=wbf[6144+i];
  }
  for(int i=threadIdx.x;i<3072;i+=256){
    int frag=i>>9, m=(i>>5)&15, k=i&31;
    int cl=k>>3, e=k&7;
    sA[frag*512 + m*32 + ((cl^(m&3))<<3) + e] = wA[i];
  }
  int wv=threadIdx.x>>6, lane=threadIdx.x&63;
  int c=lane&15, g=lane>>4;

  float stS0=0.f, stS1=0.f, stQ0=0.f, stQ1=0.f;
  __syncthreads();

  sal* yw = ybuf[wv];
  int wsw = (g^(c&3))<<3;           // chunk swizzle offset for frag reads
  f32x4 z4 = {0.f,0.f,0.f,0.f};
  int tileBase = blockIdx.x*1024 + wv*16;

  // prefetch tile 0 inputs
  float pt0,pt1,pt2, pr[9];
  {
    int r0 = tileBase + c;
    int lr = (r0 < N) ? r0 : (N-1);
    pt0=tra[lr*3+0]; pt1=tra[lr*3+1]; pt2=tra[lr*3+2];
#pragma unroll
    for(int i=0;i<9;i++) pr[i]=rot[lr*9+i];
  }

  for(int it=0; it<16; ++it, tileBase += 64){
    if(tileBase >= N) break;             // no barriers inside loop (wave-private LDS)
    int row = tileBase + c;
    bool vrow = row < N;

    // ---- consume prefetched inputs -> shared x B-frag: [t0,t1,t2,1, r0..r8, 0..0] ----
    U8 xB;
    {
      unsigned a0=cvtpk(pt0,pt1), a1=cvtpk(pt2,1.f), a2=cvtpk(pr[0],pr[1]), a3=cvtpk(pr[2],pr[3]);
      unsigned b0=cvtpk(pr[4],pr[5]), b1=cvtpk(pr[6],pr[7]), b2=cvtpk(pr[8],0.f);
      unsigned w0 = (g==0)?a0:((g==1)?b0:0u);
      unsigned w1 = (g==0)?a1:((g==1)?b1:0u);
      unsigned w2 = (g==0)?a2:((g==1)?b2:0u);
      unsigned w3 = (g==0)?a3:0u;
      xB.u = make_uint4(w0,w1,w2,w3);
    }
    // ---- issue next tile's loads early (hide under compute) ----
    {
      int r2 = tileBase + 64 + c;
      int lr2 = (r2 < N) ? r2 : (N-1);
      pt0=tra[lr2*3+0]; pt1=tra[lr2*3+1]; pt2=tra[lr2*3+2];
#pragma unroll
      for(int i=0;i<9;i++) pr[i]=rot[lr2*9+i];
    }

    // ---- first layers via MFMA: per net 2 MFMAs, D pairs concat in-lane ----
    U8 aK,aQ,aV;
#pragma unroll
    for(int nt=0;nt<3;nt++){
      U8 A1,A2;
      A1.u = *(const u4al*)&sA[(nt*2+0)*512 + c*32 + wsw];
      A2.u = *(const u4al*)&sA[(nt*2+1)*512 + c*32 + wsw];
      f32x4 d1 = MFMA16(A1.s, xB.s, z4);
      f32x4 d2 = MFMA16(A2.s, xB.s, z4);
#pragma unroll
      for(int rg=0;rg<4;rg++){ d1[rg]=fmaxf(d1[rg],0.f); d2[rg]=fmaxf(d2[rg],0.f); }
      uint4 u = make_uint4(cvtpk(d1[0],d1[1]),cvtpk(d1[2],d1[3]),
                           cvtpk(d2[0],d2[1]),cvtpk(d2[2],d2[3]));
      if(nt==0) aK.u=u; else if(nt==1) aQ.u=u; else aV.u=u;
    }

    // swapped k,q,v GEMMs: D[feature 16t+4g+rg][row c]; bias C-operands from LDS.
    f32x4 s4[4], av[4];
#pragma unroll
    for(int t=0;t<4;t++){
      U8 bk, bq, bv;
      bk.u = *(const u4al*)&sbK[(t*16+c)*32 + wsw];
      bq.u = *(const u4al*)&sbQ[(t*16+c)*32 + wsw];
      bv.u = *(const u4al*)&sbV[(t*16+c)*32 + wsw];
      f32x4 ak = MFMA16(bk.s, aK.s, *(const f4al*)&sBias[16*t+4*g]);
      f32x4 aq = MFMA16(bq.s, aQ.s, *(const f4al*)&sBias[64+16*t+4*g]);
      av[t]    = MFMA16(bv.s, aV.s, *(const f4al*)&sBias[128+16*t+4*g]);
#pragma unroll
      for(int rg=0;rg<4;rg++) s4[t][rg]=ak[rg]*aq[rg];
    }

    // ---- softmax: pairwise-tree max/sum (depth 4) + 2 cross-group shfl rounds ----
    float m0,m1,m2_,m3,m4,m5,m6,m7;
    m0=fmaxf(s4[0][0],s4[0][1]); m1=fmaxf(s4[0][2],s4[0][3]);
    m2_=fmaxf(s4[1][0],s4[1][1]); m3=fmaxf(s4[1][2],s4[1][3]);
    m4=fmaxf(s4[2][0],s4[2][1]); m5=fmaxf(s4[2][2],s4[2][3]);
    m6=fmaxf(s4[3][0],s4[3][1]); m7=fmaxf(s4[3][2],s4[3][3]);
    m0=fmaxf(m0,m1); m2_=fmaxf(m2_,m3); m4=fmaxf(m4,m5); m6=fmaxf(m6,m7);
    m0=fmaxf(m0,m2_); m4=fmaxf(m4,m6);
    float mx=fmaxf(m0,m4);
    mx=fmaxf(mx,__shfl_xor(mx,16,64));
    mx=fmaxf(mx,__shfl_xor(mx,32,64));
    float m2 = mx*L2E;
    float ee[16];
#pragma unroll
    for(int t=0;t<4;t++)
#pragma unroll
      for(int rg=0;rg<4;rg++){
        float e = exp2f(fmaf(s4[t][rg], L2E, -m2));
        s4[t][rg]=e; ee[t*4+rg]=e;
      }
#pragma unroll
    for(int i=0;i<8;i++) ee[i]+=ee[i+8];
#pragma unroll
    for(int i=0;i<4;i++) ee[i]+=ee[i+4];
    float zz=(ee[0]+ee[1])+(ee[2]+ee[3]);
    zz+=__shfl_xor(zz,16,64);
    zz+=__shfl_xor(zz,32,64);
    float inv = 1.f/zz;

    // P = e*inv*v packed IN-LANE into the two y1 A-frags (kpermD labeling)
    U8 ap0, ap1;
    {
      float p[4][4];
#pragma unroll
      for(int t=0;t<4;t++)
#pragma unroll
        for(int rg=0;rg<4;rg++) p[t][rg]=s4[t][rg]*inv*av[t][rg];
      ap0.u = make_uint4(cvtpk(p[0][0],p[0][1]),cvtpk(p[0][2],p[0][3]),
                         cvtpk(p[1][0],p[1][1]),cvtpk(p[1][2],p[1][3]));
      ap1.u = make_uint4(cvtpk(p[2][0],p[2][1]),cvtpk(p[2][2],p[2][3]),
                         cvtpk(p[3][0],p[3][1]),cvtpk(p[3][2],p[3][3]));
    }

    // y1 = P @ dW1 (b-frags from chunk-swizzled sbD)
    f32x4 acy0=z4, acy1=z4;
#pragma unroll
    for(int kc=0;kc<2;kc++){
      int dsw = ((kc*4+g)^(c&7))<<3;
      U8 b0, b1;
      b0.u = *(const u4al*)&sbD[c*64 + dsw];
      b1.u = *(const u4al*)&sbD[(16+c)*64 + dsw];
      acy0 = MFMA16((kc?ap1:ap0).s, b0.s, acy0);
      acy1 = MFMA16((kc?ap1:ap0).s, b1.s, acy1);
    }
    // mask invalid rows
#pragma unroll
    for(int rg=0;rg<4;rg++){
      if(tileBase + 4*g + rg >= N){ acy0[rg]=0.f; acy1[rg]=0.f; }
    }
    // stats
#pragma unroll
    for(int rg=0;rg<4;rg++){
      stS0+=acy0[rg]; stQ0+=acy0[rg]*acy0[rg];
      stS1+=acy1[rg]; stQ1+=acy1[rg]*acy1[rg];
    }
    // y1 store via LDS (stride 40 shorts) -> coalesced 16B
#pragma unroll
    for(int rg=0;rg<4;rg++){
      int m=4*g+rg;
      unsigned pr2 = cvtpk(acy0[rg], acy1[rg]);
      yw[m*40 + c]      = (unsigned short)pr2;
      yw[m*40 + 16 + c] = (unsigned short)(pr2>>16);
    }
    {
      u4al vv = *(const u4al*)&yw[c*40 + 8*g];
      if(vrow) *(uint4*)(y1o + (size_t)row*32 + 8*g) = vv;
    }
  }
  // per-wave stat partials -> pB[f][blockIdx*4+wv]
  stS0+=__shfl_xor(stS0,16,64); stS0+=__shfl_xor(stS0,32,64);
  stS1+=__shfl_xor(stS1,16,64); stS1+=__shfl_xor(stS1,32,64);
  stQ0+=__shfl_xor(stQ0,16,64); stQ0+=__shfl_xor(stQ0,32,64);
  stQ1+=__shfl_xor(stQ1,16,64); stQ1+=__shfl_xor(stQ1,32,64);
  if(g==0){
    int b4 = blockIdx.x*4 + wv;
    pB[c*nb4 + b4]      = stS0;
    pB[(16+c)*nb4 + b4] = stS1;
    pB[(32+c)*nb4 + b4] = stQ0;
    pB[(48+c)*nb4 + b4] = stQ1;
  }
}

// ---------------- kCM: y1(bf16) -> BN-d1 -> ReLU -> dW2 (MFMA) -> y2(bf16) + stats
__global__ __launch_bounds__(256) void kCM(const unsigned short* __restrict__ y1,
    const float* __restrict__ cst, const unsigned short* __restrict__ wbf,
    unsigned short* __restrict__ y2o, float* __restrict__ pC, int N, int nb){
  __shared__ __align__(16) unsigned short ybuf[4][256];  // per-wave 16x16 bf16
  __shared__ __align__(16) float sStat[4][32];
  int wv=threadIdx.x>>6, lane=threadIdx.x&63;
  int c=lane&15, g=lane>>4;
  U8 bD2; bD2.u = *(const uint4*)(wbf + 8192 + c*32 + 8*g);
  float sc[8], bi[8];
#pragma unroll
  for(int i=0;i<8;i++){ sc[i]=cst[192+8*g+i]; bi[i]=cst[224+8*g+i]; }
  float stS=0.f, stQ=0.f;
  unsigned short* yb = ybuf[wv];
  int tileBase = blockIdx.x*1024 + wv*16;
  f32x4 z4 = {0.f,0.f,0.f,0.f};
  // prefetch iteration 0
  uint4 w;
  {
    int r0 = tileBase + c;
    int lr = (r0 < N) ? r0 : (N-1);
    w = *(const uint4*)(y1 + (size_t)lr*32 + 8*g);
  }
  for(int it=0; it<16; ++it, tileBase += 64){
    if(tileBase >= N) break;
    int row = tileBase + c;
    bool vrow = row < N;
    uint4 cur = w;
    // prefetch next iteration
    {
      int r2 = tileBase + 64 + c;
      int lr2 = (r2 < N) ? r2 : (N-1);
      w = *(const uint4*)(y1 + (size_t)lr2*32 + 8*g);
    }
    unsigned wu[4]={cur.x,cur.y,cur.z,cur.w};
    float h[8];
#pragma unroll
    for(int j=0;j<4;j++){ h[2*j]=bflo(wu[j]); h[2*j+1]=bfhi(wu[j]); }
#pragma unroll
    for(int i=0;i<8;i++){ float x=h[i]*sc[i]+bi[i]; h[i]=fmaxf(x,0.f); }
    U8 a;
    a.u = make_uint4(cvtpk(h[0],h[1]),cvtpk(h[2],h[3]),cvtpk(h[4],h[5]),cvtpk(h[6],h[7]));
    f32x4 acc = MFMA16(a.s, bD2.s, z4);
#pragma unroll
    for(int rg=0;rg<4;rg++){
      if(tileBase + 4*g + rg >= N) acc[rg]=0.f;
      stS+=acc[rg]; stQ+=acc[rg]*acc[rg];
    }
#pragma unroll
    for(int rg=0;rg<4;rg++){
      int m=4*g+rg;
      yb[(m*16 + c) ^ ((m&3)<<2)] = f2bf(acc[rg]);
    }
    {
      int idx = (c*16 + 4*g) ^ ((c&3)<<2);
      uint2 vv = *(uint2*)&yb[idx];
      if(vrow) *(uint2*)(y2o + (size_t)row*16 + 4*g) = vv;
    }
  }
  stS+=__shfl_xor(stS,16,64); stS+=__shfl_xor(stS,32,64);
  stQ+=__shfl_xor(stQ,16,64); stQ+=__shfl_xor(stQ,32,64);
  if(g==0){ sStat[wv][c]=stS; sStat[wv][16+c]=stQ; }
  __syncthreads();
  int t=threadIdx.x;
  if(t<32) pC[t*nb + blockIdx.x] = sStat[0][t]+sStat[1][t]+sStat[2][t]+sStat[3][t];
}

// ---------------- kD: y2(bf16) -> BN-d2 -> ReLU -> dW3+db3 -> sigmoid -> out
__global__ __launch_bounds__(256) void kD(const unsigned short* __restrict__ y2,
    const float* __restrict__ cst, const float* __restrict__ dW3, const float* __restrict__ db3,
    float* __restrict__ outp, int N){
  int row=blockIdx.x*256+threadIdx.x;
  if(row>=N) return;
  const uint4* src=(const uint4*)(y2+(size_t)row*16);
  uint4 q0=src[0],q1=src[1];
  unsigned int w[8]={q0.x,q0.y,q0.z,q0.w,q1.x,q1.y,q1.z,q1.w};
  float o=db3[0];
#pragma unroll
  for(int kk=0;kk<8;kk++){
    float lo=bflo(w[kk])*cst[256+2*kk]+cst[272+2*kk];
    float hi=bfhi(w[kk])*cst[256+2*kk+1]+cst[272+2*kk+1];
    lo=lo>0.f?lo:0.f; hi=hi>0.f?hi:0.f;
    o+=lo*dW3[2*kk]+hi*dW3[2*kk+1];
  }
  outp[row]=1.f/(1.f+__expf(-o));
}

extern "C" void kernel_launch(void* const* d_in, const int* in_sizes, int n_in,
                              void* d_out, int out_size, void* d_ws, size_t ws_size,
                              hipStream_t stream){
  const float* rot=(const float*)d_in[0];
  const float* tra=(const float*)d_in[1];
  const float* kW1=(const float*)d_in[2];
  const float* kg =(const float*)d_in[3];
  const float* kb =(const float*)d_in[4];
  const float* kW2=(const float*)d_in[5];
  const float* kb2=(const float*)d_in[6];
  const float* qW1=(const float*)d_in[7];
  const float* qg =(const float*)d_in[8];
  const float* qb =(const float*)d_in[9];
  const float* qW2=(const float*)d_in[10];
  const float* qb2=(const float*)d_in[11];
  const float* vW1=(const float*)d_in[12];
  const float* vg =(const float*)d_in[13];
  const float* vb =(const float*)d_in[14];
  const float* vW2=(const float*)d_in[15];
  const float* vb2=(const float*)d_in[16];
  const float* dW1=(const float*)d_in[17];
  const float* dg1=(const float*)d_in[18];
  const float* db1=(const float*)d_in[19];
  const float* dW2=(const float*)d_in[20];
  const float* dg2=(const float*)d_in[21];
  const float* db2=(const float*)d_in[22];
  const float* dW3=(const float*)d_in[23];
  const float* db3=(const float*)d_in[24];

  int N=in_sizes[0]/9;
  int nbH=(N+1023)/1024;
  int nb4=4*nbH;

  float* ws=(float*)d_ws;
  float* cst=ws;                         // [0,1024)
  float* pA =ws+1024;                    // 63*512 -> ends 33280
  float* pB =ws+33280;                   // [64][nb4]
  float* pC =pB+(size_t)64*nb4;          // [32][nbH]
  unsigned short* wbf=(unsigned short*)(pC+(size_t)32*nbH);  // 8704 shorts
  unsigned short* wA = wbf+8704;                              // 3072 shorts

  size_t y1off=(size_t)8<<20;            // bytes
  unsigned short* y1=(unsigned short*)((char*)d_ws + y1off);
  unsigned short* y2=(unsigned short*)((char*)d_ws + y1off + (size_t)N*64);
  float invN=1.f/(float)N;
  dim3 B(256);

  kT <<<dim3(1),   B,0,stream>>>(kW2,qW2,vW2,dW1,dW2,wbf);
  kA <<<dim3(512), B,0,stream>>>(rot,tra,pA,N);
  kA2<<<dim3(1),   B,0,stream>>>(pA,512,kW1,kg,kb,qW1,qg,qb,vW1,vg,vb,cst,wA,invN);

  kHeavyM<<<dim3(nbH),B,0,stream>>>(rot,tra,wA,wbf,kb2,qb2,vb2,y1,pB,N,nb4);
  kRed<<<dim3(32),B,0,stream>>>(pB,32,nb4,dg1,db1,cst+192,invN);
  kCM<<<dim3(nbH),B,0,stream>>>(y1,cst,wbf,y2,pC,N,nbH);
  kRed<<<dim3(16),B,0,stream>>>(pC,16,nbH,dg2,db2,cst+256,invN);
  kD <<<dim3((N+255)/256),B,0,stream>>>(y2,cst,dW3,db3,(float*)d_out,N);
}

// Round 21
// 234.218 us; speedup vs baseline: 1.1420x; 1.0130x over previous
//
#include <hip/hip_runtime.h>

#define EPS 1e-5f
#define L2E 1.442695041f

typedef __attribute__((ext_vector_type(8))) short short8;
typedef __attribute__((ext_vector_type(4))) float f32x4;
#define MFMA16(a,b,c) __builtin_amdgcn_mfma_f32_16x16x32_bf16(a,b,c,0,0,0)

typedef float __attribute__((may_alias)) fal;
typedef unsigned short __attribute__((may_alias)) sal;
typedef unsigned int __attribute__((may_alias)) u32al;
typedef uint4 __attribute__((may_alias)) u4al;
typedef f32x4 __attribute__((may_alias)) f4al;

union U8 { short8 s; uint4 u; };

__device__ __forceinline__ float wred(float v){
#pragma unroll
  for(int m=32;m>=1;m>>=1) v += __shfl_xor(v,m,64);
  return v;
}

__device__ __forceinline__ unsigned short f2bf(float f){
  union{unsigned int i; float x;}v; v.x=f;
  unsigned int u=v.i;
  unsigned int r=(u + 0x7fffu + ((u>>16)&1u))>>16;
  return (unsigned short)r;
}
// single-instruction packed f32->bf16 (RNE). Verified bit-identical to f2bf pair on HW (R2==R3).
__device__ __forceinline__ unsigned cvtpk(float lo, float hi){
  unsigned r; asm("v_cvt_pk_bf16_f32 %0, %1, %2" : "=v"(r) : "v"(lo), "v"(hi)); return r;
}
__device__ __forceinline__ float bflo(unsigned int u){
  union{unsigned int i; float x;}v; v.i=u<<16; return v.x;
}
__device__ __forceinline__ float bfhi(unsigned int u){
  union{unsigned int i; float x;}v; v.i=u&0xffff0000u; return v.x;
}

// k-row permutation #1 (second-layer frags): kappa = 8g+e -> feature (e<4)?4g+e:16+4g+e-4.
__device__ __host__ __forceinline__ int kperm(int k){
  int g=k>>3, e=k&7;
  return (e<4) ? 4*g+e : 16+4*g+(e-4);
}
// k-row permutation #2 (y1-GEMM): kglobal = kc*32+8*gamma+e -> feature 16*(2kc+(e>>2))+4*gamma+(e&3).
__device__ __host__ __forceinline__ int kpermD(int kg){
  int kc=kg>>5, kk=kg&31, gm=kk>>3, e=kk&7;
  return 16*(2*kc+(e>>2)) + 4*gm + (e&3);
}

// ---------------- kA: input moments, 4 rows/thread with float4 loads (fully coalesced)
__global__ __launch_bounds__(256) void kA(const float* __restrict__ rot, const float* __restrict__ tra,
                                          float* __restrict__ pA, int N){
  float a[63];
#pragma unroll
  for(int i=0;i<63;i++) a[i]=0.f;
  int stride = gridDim.x*blockDim.x;
  int nch = N>>2;
  for(int ch=blockIdx.x*blockDim.x+threadIdx.x; ch<nch; ch+=stride){
    float tt[12], rr[36];
    {
      const float4* tp = (const float4*)(tra + (size_t)ch*12);
      const float4* rp = (const float4*)(rot + (size_t)ch*36);
#pragma unroll
      for(int i=0;i<3;i++) *(float4*)&tt[4*i]=tp[i];
#pragma unroll
      for(int i=0;i<9;i++) *(float4*)&rr[4*i]=rp[i];
    }
#pragma unroll
    for(int w=0;w<4;w++){
      const float* t=&tt[3*w];
      const float* r=&rr[9*w];
#pragma unroll
      for(int i=0;i<3;i++) a[i]+=t[i];
#pragma unroll
      for(int i=0;i<3;i++)
#pragma unroll
        for(int j=i;j<3;j++) a[3 + i*3 - (i*(i-1))/2 + (j-i)] += t[i]*t[j];
#pragma unroll
      for(int i=0;i<9;i++) a[9+i]+=r[i];
#pragma unroll
      for(int i=0;i<9;i++)
#pragma unroll
        for(int j=i;j<9;j++) a[18 + i*9 - (i*(i-1))/2 + (j-i)] += r[i]*r[j];
    }
  }
  if(blockIdx.x==0 && threadIdx.x==0){
    for(int row=(nch<<2); row<N; ++row){
      const float* t=tra+ (size_t)row*3;
      const float* r=rot+ (size_t)row*9;
#pragma unroll
      for(int i=0;i<3;i++) a[i]+=t[i];
#pragma unroll
      for(int i=0;i<3;i++)
#pragma unroll
        for(int j=i;j<3;j++) a[3 + i*3 - (i*(i-1))/2 + (j-i)] += t[i]*t[j];
#pragma unroll
      for(int i=0;i<9;i++) a[9+i]+=r[i];
#pragma unroll
      for(int i=0;i<9;i++)
#pragma unroll
        for(int j=i;j<9;j++) a[18 + i*9 - (i*(i-1))/2 + (j-i)] += r[i]*r[j];
    }
  }
#pragma unroll
  for(int i=0;i<63;i++) a[i]=wred(a[i]);
  __shared__ __align__(16) float lds[4][63];
  int wave=threadIdx.x>>6, lane=threadIdx.x&63;
  if(lane==0){
#pragma unroll
    for(int i=0;i<63;i++) lds[wave][i]=a[i];
  }
  __syncthreads();
  int t=threadIdx.x;
  if(t<63) pA[t*gridDim.x + blockIdx.x] = lds[0][t]+lds[1][t]+lds[2][t]+lds[3][t];
}

// ---------------- kA2: kT's weight transposes + reduce moments -> BN1 consts -> bf16 A-frags.
// wbf layout (shorts): kW2T[64][32] @0 | qW2T @2048 | vW2T @4096 | dW1T[32][64] @6144 | dW2T[16][32] @8192
__global__ __launch_bounds__(256) void kA2(const float* __restrict__ pA, int nb,
    const float* __restrict__ kW1, const float* __restrict__ kg, const float* __restrict__ kb,
    const float* __restrict__ qW1, const float* __restrict__ qg, const float* __restrict__ qb,
    const float* __restrict__ vW1, const float* __restrict__ vg, const float* __restrict__ vb,
    const float* __restrict__ kW2, const float* __restrict__ qW2, const float* __restrict__ vW2,
    const float* __restrict__ dW1, const float* __restrict__ dW2,
    float* __restrict__ cst, unsigned short* __restrict__ wA, unsigned short* __restrict__ wbf,
    float invN){
  // ---- kT work (independent of stats) ----
  for(int idx=threadIdx.x; idx<2048; idx+=256){
    int k=idx&31, c=idx>>5;
    int f=kperm(k);
    wbf[c*32+k]       = f2bf(kW2[f*64+c]);
    wbf[2048+c*32+k]  = f2bf(qW2[f*64+c]);
    wbf[4096+c*32+k]  = f2bf(vW2[f*64+c]);
  }
  for(int idx=threadIdx.x; idx<2048; idx+=256){
    int f=idx&31, kg2=idx>>5;
    wbf[6144 + f*64 + kg2] = f2bf(dW1[kpermD(kg2)*32 + f]);
  }
  for(int idx=threadIdx.x; idx<512; idx+=256){
    int k=idx>>4, f=idx&15;
    wbf[8192 + f*32 + k] = f2bf(dW2[idx]);
  }
  // ---- stats reduce + BN1 fold ----
  __shared__ __align__(16) float tmp[63][4];
  __shared__ __align__(16) float mom[63];
  __shared__ __align__(16) float sSc[96];
  __shared__ __align__(16) float sBi[96];
  int t=threadIdx.x;
  if(t<252){
    int f=t>>2, q=t&3;
    int per=nb/4;
    float s=0.f;
    for(int i=0;i<per;i++) s+=pA[f*nb + q*per + i];
    tmp[f][q]=s;
  }
  __syncthreads();
  if(t<63) mom[t]=tmp[t][0]+tmp[t][1]+tmp[t][2]+tmp[t][3];
  __syncthreads();
  if(t<96){
    int net=t>>5, j=t&31;
    const float* W1; const float* g; const float* b; int din, sbase, mbase, obase;
    if(net==0){W1=kW1;g=kg;b=kb;din=3;sbase=0;mbase=3;obase=0;}
    else if(net==1){W1=qW1;g=qg;b=qb;din=9;sbase=9;mbase=18;obase=64;}
    else {W1=vW1;g=vg;b=vb;din=3;sbase=0;mbase=3;obase=128;}
    float mean=0.f, ex2=0.f;
    for(int i=0;i<din;i++){
      float wi=W1[i*32+j];
      mean += mom[sbase+i]*wi;
      int rowb = mbase + i*din - (i*(i-1))/2;
      for(int i2=i;i2<din;i2++){
        float w2=W1[i2*32+j];
        float m=mom[rowb + (i2-i)];
        ex2 += ((i2==i)?1.f:2.f)*wi*w2*m;
      }
    }
    mean*=invN; ex2*=invN;
    float var=ex2-mean*mean;
    float sc=g[j]*rsqrtf(var+EPS);
    float bi=b[j]-mean*sc;
    cst[obase+j]=sc; cst[obase+32+j]=bi;
    sSc[net*32+j]=sc; sBi[net*32+j]=bi;
  }
  __syncthreads();
  for(int i=threadIdx.x; i<3072; i+=256){
    int frag=i>>9, m=(i>>5)&15, k=i&31;
    int net=frag>>1, half=frag&1;
    int f = half*16+m;
    float v=0.f;
    if(net==0){
      if(k<3) v=kW1[k*32+f]*sSc[f];
      else if(k==3) v=sBi[f];
    } else if(net==1){
      if(k>=4 && k<13) v=qW1[(k-4)*32+f]*sSc[32+f];
      else if(k==3) v=sBi[32+f];
    } else {
      if(k<3) v=vW1[k*32+f]*sSc[64+f];
      else if(k==3) v=sBi[64+f];
    }
    wA[i]=f2bf(v);
  }
}

// ---------------- kRed: reduce per-block {sum,sumsq} partials -> BN scale/bias
__global__ __launch_bounds__(256) void kRed(const float* __restrict__ part, int nf, int nb,
    const float* __restrict__ g, const float* __restrict__ b, float* __restrict__ cstOut, float invN){
  int f=blockIdx.x;
  float s1=0.f,s2=0.f;
  for(int i=threadIdx.x;i<nb;i+=256){ s1+=part[f*nb+i]; s2+=part[(nf+f)*nb+i]; }
  s1=wred(s1); s2=wred(s2);
  __shared__ __align__(16) float l1[4],l2[4];
  int wave=threadIdx.x>>6;
  if((threadIdx.x&63)==0){l1[wave]=s1;l2[wave]=s2;}
  __syncthreads();
  if(threadIdx.x==0){
    float a=l1[0]+l1[1]+l1[2]+l1[3];
    float c=l2[0]+l2[1]+l2[2]+l2[3];
    float mean=a*invN;
    float var=c*invN-mean*mean;
    float sc=g[f]*rsqrtf(var+EPS);
    float bi=b[f]-mean*sc;
    cstOut[f]=sc; cstOut[nf+f]=bi;
  }
}

// ---------------- kHeavyM: full-MFMA per-row pipeline -> y1(bf16) + BN-d1 stats
// R18 structure + maskless fast path; inv applied BEFORE y1-MFMA (lane-local row c;
// folding it after the MFMA is layout-illegal: D rows are 4g+rg, not c — R19 bug).
__global__ __launch_bounds__(256) void kHeavyM(
    const float* __restrict__ rot, const float* __restrict__ tra,
    const unsigned short* __restrict__ wA, const unsigned short* __restrict__ wbf,
    const float* __restrict__ kb2, const float* __restrict__ qb2, const float* __restrict__ vb2,
    unsigned short* __restrict__ y1o, float* __restrict__ pB, int N, int nb4)
{
  __shared__ __align__(16) float sBias[192];
  __shared__ __align__(16) unsigned short sbK[2048];
  __shared__ __align__(16) unsigned short sbQ[2048];
  __shared__ __align__(16) unsigned short sbV[2048];
  __shared__ __align__(16) unsigned short sbD[2048];
  __shared__ __align__(16) unsigned short sA[3072];
  __shared__ __align__(16) sal ybuf[4][640];
  if(threadIdx.x<192){
    int i=threadIdx.x;
    sBias[i] = (i<64)?kb2[i]:((i<128)?qb2[i-64]:vb2[i-128]);
  }
  for(int i=threadIdx.x;i<2048;i+=256){
    int e=i&7;
    int rK=i>>5, clK=(i>>3)&3;
    int dK = rK*32 + ((clK^(rK&3))<<3) + e;
    sbK[dK]=wbf[i]; sbQ[dK]=wbf[2048+i]; sbV[dK]=wbf[4096+i];
    int rD=i>>6, clD=(i>>3)&7;
    int dD = rD*64 + ((clD^(rD&7))<<3) + e;
    sbD[dD]=wbf[6144+i];
  }
  for(int i=threadIdx.x;i<3072;i+=256){
    int frag=i>>9, m=(i>>5)&15, k=i&31;
    int cl=k>>3, e=k&7;
    sA[frag*512 + m*32 + ((cl^(m&3))<<3) + e] = wA[i];
  }
  int wv=threadIdx.x>>6, lane=threadIdx.x&63;
  int c=lane&15, g=lane>>4;

  float stS0=0.f, stS1=0.f, stQ0=0.f, stQ1=0.f;
  __syncthreads();

  sal* yw = ybuf[wv];
  int wsw = (g^(c&3))<<3;
  f32x4 z4 = {0.f,0.f,0.f,0.f};
  int tileBase = blockIdx.x*1024 + wv*16;
  bool fullBlk = (blockIdx.x*1024 + 1024) <= N;   // block-uniform

  // prefetch tile 0 inputs
  float pt0,pt1,pt2, pr[9];
  {
    int r0 = tileBase + c;
    int lr = (r0 < N) ? r0 : (N-1);
    pt0=tra[lr*3+0]; pt1=tra[lr*3+1]; pt2=tra[lr*3+2];
#pragma unroll
    for(int i=0;i<9;i++) pr[i]=rot[lr*9+i];
  }

  for(int it=0; it<16; ++it, tileBase += 64){
    if(tileBase >= N) break;
    int row = tileBase + c;
    bool vrow = fullBlk || (row < N);

    U8 xB;
    {
      unsigned a0=cvtpk(pt0,pt1), a1=cvtpk(pt2,1.f), a2=cvtpk(pr[0],pr[1]), a3=cvtpk(pr[2],pr[3]);
      unsigned b0=cvtpk(pr[4],pr[5]), b1=cvtpk(pr[6],pr[7]), b2=cvtpk(pr[8],0.f);
      unsigned w0 = (g==0)?a0:((g==1)?b0:0u);
      unsigned w1 = (g==0)?a1:((g==1)?b1:0u);
      unsigned w2 = (g==0)?a2:((g==1)?b2:0u);
      unsigned w3 = (g==0)?a3:0u;
      xB.u = make_uint4(w0,w1,w2,w3);
    }
    {
      int r2 = tileBase + 64 + c;
      int lr2 = (r2 < N) ? r2 : (N-1);
      pt0=tra[lr2*3+0]; pt1=tra[lr2*3+1]; pt2=tra[lr2*3+2];
#pragma unroll
      for(int i=0;i<9;i++) pr[i]=rot[lr2*9+i];
    }

    U8 aK,aQ,aV;
#pragma unroll
    for(int nt=0;nt<3;nt++){
      U8 A1,A2;
      A1.u = *(const u4al*)&sA[(nt*2+0)*512 + c*32 + wsw];
      A2.u = *(const u4al*)&sA[(nt*2+1)*512 + c*32 + wsw];
      f32x4 d1 = MFMA16(A1.s, xB.s, z4);
      f32x4 d2 = MFMA16(A2.s, xB.s, z4);
#pragma unroll
      for(int rg=0;rg<4;rg++){ d1[rg]=fmaxf(d1[rg],0.f); d2[rg]=fmaxf(d2[rg],0.f); }
      uint4 u = make_uint4(cvtpk(d1[0],d1[1]),cvtpk(d1[2],d1[3]),
                           cvtpk(d2[0],d2[1]),cvtpk(d2[2],d2[3]));
      if(nt==0) aK.u=u; else if(nt==1) aQ.u=u; else aV.u=u;
    }

    f32x4 s4[4], av[4];
#pragma unroll
    for(int t=0;t<4;t++){
      U8 bk, bq, bv;
      bk.u = *(const u4al*)&sbK[(t*16+c)*32 + wsw];
      bq.u = *(const u4al*)&sbQ[(t*16+c)*32 + wsw];
      bv.u = *(const u4al*)&sbV[(t*16+c)*32 + wsw];
      f32x4 ak = MFMA16(bk.s, aK.s, *(const f4al*)&sBias[16*t+4*g]);
      f32x4 aq = MFMA16(bq.s, aQ.s, *(const f4al*)&sBias[64+16*t+4*g]);
      av[t]    = MFMA16(bv.s, aV.s, *(const f4al*)&sBias[128+16*t+4*g]);
#pragma unroll
      for(int rg=0;rg<4;rg++) s4[t][rg]=ak[rg]*aq[rg];
    }

    // softmax: pairwise-tree max/sum + 2 cross-group shfl rounds
    float m0,m1,m2_,m3,m4,m5,m6,m7;
    m0=fmaxf(s4[0][0],s4[0][1]); m1=fmaxf(s4[0][2],s4[0][3]);
    m2_=fmaxf(s4[1][0],s4[1][1]); m3=fmaxf(s4[1][2],s4[1][3]);
    m4=fmaxf(s4[2][0],s4[2][1]); m5=fmaxf(s4[2][2],s4[2][3]);
    m6=fmaxf(s4[3][0],s4[3][1]); m7=fmaxf(s4[3][2],s4[3][3]);
    m0=fmaxf(m0,m1); m2_=fmaxf(m2_,m3); m4=fmaxf(m4,m5); m6=fmaxf(m6,m7);
    m0=fmaxf(m0,m2_); m4=fmaxf(m4,m6);
    float mx=fmaxf(m0,m4);
    mx=fmaxf(mx,__shfl_xor(mx,16,64));
    mx=fmaxf(mx,__shfl_xor(mx,32,64));
    float m2 = mx*L2E;
    float ee[16];
#pragma unroll
    for(int t=0;t<4;t++)
#pragma unroll
      for(int rg=0;rg<4;rg++){
        float e = exp2f(fmaf(s4[t][rg], L2E, -m2));
        s4[t][rg]=e; ee[t*4+rg]=e;
      }
#pragma unroll
    for(int i=0;i<8;i++) ee[i]+=ee[i+8];
#pragma unroll
    for(int i=0;i<4;i++) ee[i]+=ee[i+4];
    float zz=(ee[0]+ee[1])+(ee[2]+ee[3]);
    zz+=__shfl_xor(zz,16,64);
    zz+=__shfl_xor(zz,32,64);
    float inv = 1.f/zz;

    // P = e*inv*v packed IN-LANE into the two y1 A-frags (kpermD labeling).
    // inv MUST be applied here (lane-local row c); post-MFMA rows are 4g+rg.
    U8 ap0, ap1;
    {
      float p[4][4];
#pragma unroll
      for(int t=0;t<4;t++)
#pragma unroll
        for(int rg=0;rg<4;rg++) p[t][rg]=s4[t][rg]*inv*av[t][rg];
      ap0.u = make_uint4(cvtpk(p[0][0],p[0][1]),cvtpk(p[0][2],p[0][3]),
                         cvtpk(p[1][0],p[1][1]),cvtpk(p[1][2],p[1][3]));
      ap1.u = make_uint4(cvtpk(p[2][0],p[2][1]),cvtpk(p[2][2],p[2][3]),
                         cvtpk(p[3][0],p[3][1]),cvtpk(p[3][2],p[3][3]));
    }

    // y1 = P @ dW1 (b-frags from chunk-swizzled sbD)
    f32x4 acy0=z4, acy1=z4;
#pragma unroll
    for(int kc=0;kc<2;kc++){
      int dsw = ((kc*4+g)^(c&7))<<3;
      U8 b0, b1;
      b0.u = *(const u4al*)&sbD[c*64 + dsw];
      b1.u = *(const u4al*)&sbD[(16+c)*64 + dsw];
      acy0 = MFMA16((kc?ap1:ap0).s, b0.s, acy0);
      acy1 = MFMA16((kc?ap1:ap0).s, b1.s, acy1);
    }
    if(!fullBlk){
#pragma unroll
      for(int rg=0;rg<4;rg++){
        if(tileBase + 4*g + rg >= N){ acy0[rg]=0.f; acy1[rg]=0.f; }
      }
    }
    // stats
#pragma unroll
    for(int rg=0;rg<4;rg++){
      stS0+=acy0[rg]; stQ0+=acy0[rg]*acy0[rg];
      stS1+=acy1[rg]; stQ1+=acy1[rg]*acy1[rg];
    }
    // y1 store via LDS (stride 40 shorts) -> coalesced 16B
#pragma unroll
    for(int rg=0;rg<4;rg++){
      int m=4*g+rg;
      unsigned pr2 = cvtpk(acy0[rg], acy1[rg]);
      yw[m*40 + c]      = (unsigned short)pr2;
      yw[m*40 + 16 + c] = (unsigned short)(pr2>>16);
    }
    {
      u4al vv = *(const u4al*)&yw[c*40 + 8*g];
      if(vrow) *(uint4*)(y1o + (size_t)row*32 + 8*g) = vv;
    }
  }
  // per-wave stat partials -> pB[f][blockIdx*4+wv]
  stS0+=__shfl_xor(stS0,16,64); stS0+=__shfl_xor(stS0,32,64);
  stS1+=__shfl_xor(stS1,16,64); stS1+=__shfl_xor(stS1,32,64);
  stQ0+=__shfl_xor(stQ0,16,64); stQ0+=__shfl_xor(stQ0,32,64);
  stQ1+=__shfl_xor(stQ1,16,64); stQ1+=__shfl_xor(stQ1,32,64);
  if(g==0){
    int b4 = blockIdx.x*4 + wv;
    pB[c*nb4 + b4]      = stS0;
    pB[(16+c)*nb4 + b4] = stS1;
    pB[(32+c)*nb4 + b4] = stQ0;
    pB[(48+c)*nb4 + b4] = stQ1;
  }
}

// ---------------- kCM: y1(bf16) -> BN-d1 -> ReLU -> dW2 (MFMA) -> y2(bf16) + stats
__global__ __launch_bounds__(256) void kCM(const unsigned short* __restrict__ y1,
    const float* __restrict__ cst, const unsigned short* __restrict__ wbf,
    unsigned short* __restrict__ y2o, float* __restrict__ pC, int N, int nb){
  __shared__ __align__(16) unsigned short ybuf[4][256];
  __shared__ __align__(16) float sStat[4][32];
  int wv=threadIdx.x>>6, lane=threadIdx.x&63;
  int c=lane&15, g=lane>>4;
  U8 bD2; bD2.u = *(const uint4*)(wbf + 8192 + c*32 + 8*g);
  float sc[8], bi[8];
#pragma unroll
  for(int i=0;i<8;i++){ sc[i]=cst[192+8*g+i]; bi[i]=cst[224+8*g+i]; }
  float stS=0.f, stQ=0.f;
  unsigned short* yb = ybuf[wv];
  int tileBase = blockIdx.x*1024 + wv*16;
  bool fullBlk = (blockIdx.x*1024 + 1024) <= N;
  f32x4 z4 = {0.f,0.f,0.f,0.f};
  uint4 w;
  {
    int r0 = tileBase + c;
    int lr = (r0 < N) ? r0 : (N-1);
    w = *(const uint4*)(y1 + (size_t)lr*32 + 8*g);
  }
  for(int it=0; it<16; ++it, tileBase += 64){
    if(tileBase >= N) break;
    int row = tileBase + c;
    bool vrow = fullBlk || (row < N);
    uint4 cur = w;
    {
      int r2 = tileBase + 64 + c;
      int lr2 = (r2 < N) ? r2 : (N-1);
      w = *(const uint4*)(y1 + (size_t)lr2*32 + 8*g);
    }
    unsigned wu[4]={cur.x,cur.y,cur.z,cur.w};
    float h[8];
#pragma unroll
    for(int j=0;j<4;j++){ h[2*j]=bflo(wu[j]); h[2*j+1]=bfhi(wu[j]); }
#pragma unroll
    for(int i=0;i<8;i++){ float x=h[i]*sc[i]+bi[i]; h[i]=fmaxf(x,0.f); }
    U8 a;
    a.u = make_uint4(cvtpk(h[0],h[1]),cvtpk(h[2],h[3]),cvtpk(h[4],h[5]),cvtpk(h[6],h[7]));
    f32x4 acc = MFMA16(a.s, bD2.s, z4);
    if(!fullBlk){
#pragma unroll
      for(int rg=0;rg<4;rg++){
        if(tileBase + 4*g + rg >= N) acc[rg]=0.f;
      }
    }
#pragma unroll
    for(int rg=0;rg<4;rg++){ stS+=acc[rg]; stQ+=acc[rg]*acc[rg]; }
#pragma unroll
    for(int rg=0;rg<4;rg++){
      int m=4*g+rg;
      yb[(m*16 + c) ^ ((m&3)<<2)] = f2bf(acc[rg]);
    }
    {
      int idx = (c*16 + 4*g) ^ ((c&3)<<2);
      uint2 vv = *(uint2*)&yb[idx];
      if(vrow) *(uint2*)(y2o + (size_t)row*16 + 4*g) = vv;
    }
  }
  stS+=__shfl_xor(stS,16,64); stS+=__shfl_xor(stS,32,64);
  stQ+=__shfl_xor(stQ,16,64); stQ+=__shfl_xor(stQ,32,64);
  if(g==0){ sStat[wv][c]=stS; sStat[wv][16+c]=stQ; }
  __syncthreads();
  int t=threadIdx.x;
  if(t<32) pC[t*nb + blockIdx.x] = sStat[0][t]+sStat[1][t]+sStat[2][t]+sStat[3][t];
}

// ---------------- kD: y2(bf16) -> BN-d2 -> ReLU -> dW3+db3 -> sigmoid -> out
__global__ __launch_bounds__(256) void kD(const unsigned short* __restrict__ y2,
    const float* __restrict__ cst, const float* __restrict__ dW3, const float* __restrict__ db3,
    float* __restrict__ outp, int N){
  int row=blockIdx.x*256+threadIdx.x;
  if(row>=N) return;
  const uint4* src=(const uint4*)(y2+(size_t)row*16);
  uint4 q0=src[0],q1=src[1];
  unsigned int w[8]={q0.x,q0.y,q0.z,q0.w,q1.x,q1.y,q1.z,q1.w};
  float o=db3[0];
#pragma unroll
  for(int kk=0;kk<8;kk++){
    float lo=bflo(w[kk])*cst[256+2*kk]+cst[272+2*kk];
    float hi=bfhi(w[kk])*cst[256+2*kk+1]+cst[272+2*kk+1];
    lo=lo>0.f?lo:0.f; hi=hi>0.f?hi:0.f;
    o+=lo*dW3[2*kk]+hi*dW3[2*kk+1];
  }
  outp[row]=1.f/(1.f+__expf(-o));
}

extern "C" void kernel_launch(void* const* d_in, const int* in_sizes, int n_in,
                              void* d_out, int out_size, void* d_ws, size_t ws_size,
                              hipStream_t stream){
  const float* rot=(const float*)d_in[0];
  const float* tra=(const float*)d_in[1];
  const float* kW1=(const float*)d_in[2];
  const float* kg =(const float*)d_in[3];
  const float* kb =(const float*)d_in[4];
  const float* kW2=(const float*)d_in[5];
  const float* kb2=(const float*)d_in[6];
  const float* qW1=(const float*)d_in[7];
  const float* qg =(const float*)d_in[8];
  const float* qb =(const float*)d_in[9];
  const float* qW2=(const float*)d_in[10];
  const float* qb2=(const float*)d_in[11];
  const float* vW1=(const float*)d_in[12];
  const float* vg =(const float*)d_in[13];
  const float* vb =(const float*)d_in[14];
  const float* vW2=(const float*)d_in[15];
  const float* vb2=(const float*)d_in[16];
  const float* dW1=(const float*)d_in[17];
  const float* dg1=(const float*)d_in[18];
  const float* db1=(const float*)d_in[19];
  const float* dW2=(const float*)d_in[20];
  const float* dg2=(const float*)d_in[21];
  const float* db2=(const float*)d_in[22];
  const float* dW3=(const float*)d_in[23];
  const float* db3=(const float*)d_in[24];

  int N=in_sizes[0]/9;
  int nbH=(N+1023)/1024;
  int nb4=4*nbH;

  float* ws=(float*)d_ws;
  float* cst=ws;                         // [0,1024)
  float* pA =ws+1024;                    // 63*512 -> ends 33280
  float* pB =ws+33280;                   // [64][nb4]
  float* pC =pB+(size_t)64*nb4;          // [32][nbH]
  unsigned short* wbf=(unsigned short*)(pC+(size_t)32*nbH);  // 8704 shorts
  unsigned short* wA = wbf+8704;                              // 3072 shorts

  size_t y1off=(size_t)8<<20;            // bytes
  unsigned short* y1=(unsigned short*)((char*)d_ws + y1off);
  unsigned short* y2=(unsigned short*)((char*)d_ws + y1off + (size_t)N*64);
  float invN=1.f/(float)N;
  dim3 B(256);

  kA <<<dim3(512), B,0,stream>>>(rot,tra,pA,N);
  kA2<<<dim3(1),   B,0,stream>>>(pA,512,kW1,kg,kb,qW1,qg,qb,vW1,vg,vb,
                                 kW2,qW2,vW2,dW1,dW2,cst,wA,wbf,invN);

  kHeavyM<<<dim3(nbH),B,0,stream>>>(rot,tra,wA,wbf,kb2,qb2,vb2,y1,pB,N,nb4);
  kRed<<<dim3(32),B,0,stream>>>(pB,32,nb4,dg1,db1,cst+192,invN);
  kCM<<<dim3(nbH),B,0,stream>>>(y1,cst,wbf,y2,pC,N,nbH);
  kRed<<<dim3(16),B,0,stream>>>(pC,16,nbH,dg2,db2,cst+256,invN);
  kD <<<dim3((N+255)/256),B,0,stream>>>(y2,cst,dW3,db3,(float*)d_out,N);
}